// Round 3
// baseline (1582.889 us; speedup 1.0000x reference)
//
#include <hip/hip_runtime.h>

#define SS 512
#define HH 768
#define PP 240
#define CCOMP 5
#define NBLK 704

typedef unsigned short u16;
typedef __attribute__((ext_vector_type(8))) short bf16x8;   // 8 bf16 in 4 VGPRs
typedef __attribute__((ext_vector_type(4))) float f32x4;

__device__ __forceinline__ u16 f2bf(float f) {
    union { float f; unsigned int i; } v; v.f = f;
    unsigned int x = v.i;
    unsigned int lsb = (x >> 16) & 1u;
    x += 0x7fffu + lsb;
    return (u16)(x >> 16);
}

__device__ __forceinline__ float ftanh(float x) {
    float xc = fminf(fmaxf(x, -15.f), 15.f);
    float e = __expf(2.f * xc);
    return (e - 1.f) / (e + 1.f);
}

// async global->LDS, 16B per lane; dest = wave-uniform base + lane*16
__device__ __forceinline__ void gl_lds16(const void* g, void* l) {
    __builtin_amdgcn_global_load_lds(
        (const __attribute__((address_space(1))) unsigned int*)g,
        (__attribute__((address_space(3))) unsigned int*)l, 16, 0, 0);
}

// software grid barrier: producer release (threadfence = agent-scope wb) +
// device-scope atomic arrive + acquire spin + consumer-side inv fence.
__device__ __forceinline__ void gridbar(unsigned int* c) {
    __threadfence();
    __syncthreads();
    if (threadIdx.x == 0) {
        __hip_atomic_fetch_add(c, 1u, __ATOMIC_ACQ_REL, __HIP_MEMORY_SCOPE_AGENT);
        while (__hip_atomic_load(c, __ATOMIC_ACQUIRE, __HIP_MEMORY_SCOPE_AGENT) < NBLK)
            __builtin_amdgcn_s_sleep(2);
    }
    __syncthreads();
    __threadfence();
}

struct Params {
    const float* lhs; const int* starts; const int* lens; const int* comps; const int* rels;
    const float* comp_w1; const float* comp_b1; const float* comp_w2; const float* comp_b2;
    const float* wq; const float* wk; const float* wv;
    const float* ln_g; const float* ln_b;
    const float* rel_w1; const float* rel_b1; const float* rel_w2; const float* rel_b2;
    float* out;
    float* pooled; float* y2; float* Z; float* comp_p; float* rel_p;
    u16* pooled_bf; u16* x_bf; u16* wcat_t; u16* relw_t;
    unsigned int* bar;
};

// 64x64-tile bf16 MFMA GEMM body: global_load_lds staging, XOR swizzle, 1-barrier dbuf.
// K = 768 fixed. A rows at Abase (row-major K-contig), B rows at Bbase (row-major K-contig).
__device__ __forceinline__ void gemm_tile(
    const u16* Abase, const u16* Bbase, u16* AsR, u16* BsR,
    int row0, int ccol0, int tid, f32x4 acc[2][2]) {
    int lane = tid & 63, w = tid >> 6;
    int q = lane >> 4, l15 = lane & 15;
    int wm = (w & 1) * 32, wn = (w >> 1) * 32;

    int srow = w * 8 + (lane >> 3);               // 0..31 (second issue adds +32)
    int sxs = ((lane & 7) * 16) ^ ((srow & 7) << 4);
    const char* gA0 = (const char*)(Abase + (size_t)(row0 + srow) * 768) + sxs;
    const char* gA1 = gA0 + (size_t)32 * 768 * 2;
    const char* gB0 = (const char*)(Bbase + (size_t)(ccol0 + srow) * 768) + sxs;
    const char* gB1 = gB0 + (size_t)32 * 768 * 2;
    char* lA = (char*)AsR + w * 1024;
    char* lB = (char*)BsR + w * 1024;

#pragma unroll
    for (int i = 0; i < 2; ++i)
#pragma unroll
        for (int j = 0; j < 2; ++j) acc[i][j] = (f32x4){0.f, 0.f, 0.f, 0.f};

#define STAGE_T(BUF, KB) do { \
        gl_lds16(gA0 + (KB), lA + (BUF) * 8192); \
        gl_lds16(gA1 + (KB), lA + (BUF) * 8192 + 4096); \
        gl_lds16(gB0 + (KB), lB + (BUF) * 8192); \
        gl_lds16(gB1 + (KB), lB + (BUF) * 8192 + 4096); \
    } while (0)

    STAGE_T(0, 0);
    asm volatile("s_waitcnt vmcnt(0)" ::: "memory");
    __syncthreads();
    int cur = 0;
    for (int t = 0; t < 12; ++t) {
        if (t < 11) STAGE_T(cur ^ 1, (t + 1) * 128);
        const char* Ab = (const char*)AsR + cur * 8192;
        const char* Bb = (const char*)BsR + cur * 8192;
#pragma unroll
        for (int ks = 0; ks < 2; ++ks) {
            int o = ks * 64 + q * 16;
            int Ra0 = wm + l15, Ra1 = wm + 16 + l15;
            int Rb0 = wn + l15, Rb1 = wn + 16 + l15;
            bf16x8 a0 = *(const bf16x8*)(Ab + Ra0 * 128 + (o ^ ((Ra0 & 7) << 4)));
            bf16x8 a1 = *(const bf16x8*)(Ab + Ra1 * 128 + (o ^ ((Ra1 & 7) << 4)));
            bf16x8 b0 = *(const bf16x8*)(Bb + Rb0 * 128 + (o ^ ((Rb0 & 7) << 4)));
            bf16x8 b1 = *(const bf16x8*)(Bb + Rb1 * 128 + (o ^ ((Rb1 & 7) << 4)));
            acc[0][0] = __builtin_amdgcn_mfma_f32_16x16x32_bf16(a0, b0, acc[0][0], 0, 0, 0);
            acc[0][1] = __builtin_amdgcn_mfma_f32_16x16x32_bf16(a0, b1, acc[0][1], 0, 0, 0);
            acc[1][0] = __builtin_amdgcn_mfma_f32_16x16x32_bf16(a1, b0, acc[1][0], 0, 0, 0);
            acc[1][1] = __builtin_amdgcn_mfma_f32_16x16x32_bf16(a1, b1, acc[1][1], 0, 0, 0);
        }
        asm volatile("s_waitcnt vmcnt(0)" ::: "memory");
        __syncthreads();
        cur ^= 1;
    }
#undef STAGE_T
}

__global__ __launch_bounds__(256, 4) void fused_kernel(Params p) {
    __shared__ u16 As[2][4096];
    __shared__ u16 Bs[2][4096];
    __shared__ float red[8];
    int tid = threadIdx.x;
    int lane = tid & 63, w = tid >> 6;
    int q = lane >> 4, l15 = lane & 15;
    int wm = (w & 1) * 32, wn = (w >> 1) * 32;

    // ================= Phase A: span pooling (units 0..1023) + weight prep (1024..3903) ==========
    for (int u = blockIdx.x; u < 3904; u += NBLK) {
        if (u < 1024) {
            if (tid < 192) {
                int st = p.starts[u];
                int ln = p.lens[u];
                int b = u >> 4;
                const float4* base = (const float4*)(p.lhs + ((size_t)b * SS + st) * HH);
                float4 a = {0.f, 0.f, 0.f, 0.f};
                for (int s = 0; s <= ln; ++s) {
                    float4 v = base[s * 192 + tid];
                    a.x += v.x; a.y += v.y; a.z += v.z; a.w += v.w;
                }
                float inv = 1.0f / (float)(ln + 1);
                a.x *= inv; a.y *= inv; a.z *= inv; a.w *= inv;
                *(float4*)(p.pooled + (size_t)u * HH + tid * 4) = a;
                ushort4 ub = { f2bf(a.x), f2bf(a.y), f2bf(a.z), f2bf(a.w) };
                *(ushort4*)(p.pooled_bf + (size_t)u * HH + tid * 4) = ub;
            }
        } else {
            int blk = u - 1024;
            const float* W; int ldw, nt; u16* outp;
            if (blk < 384)        {             W = p.comp_w1; ldw = 512; nt = 16; outp = p.wcat_t; }
            else if (blk < 960)   { blk -= 384; W = p.wq;  ldw = 768; nt = 24; outp = p.wcat_t + (size_t)512 * 768; }
            else if (blk < 1536)  { blk -= 960; W = p.wk;  ldw = 768; nt = 24; outp = p.wcat_t + (size_t)1280 * 768; }
            else if (blk < 2112)  { blk -= 1536; W = p.wv; ldw = 768; nt = 24; outp = p.wcat_t + (size_t)2048 * 768; }
            else if (blk < 2496)  { blk -= 2112; W = p.rel_w1; ldw = 512; nt = 16; outp = p.relw_t; }
            else                  { blk -= 2496; W = p.rel_w1 + (size_t)768 * 512; ldw = 512; nt = 16; outp = p.relw_t + (size_t)512 * 768; }
            int tk = blk / nt, tn = blk % nt;
            int k0 = tk * 32, n0 = tn * 32;
            u16 (*Ls)[36] = (u16(*)[36])As;   // alias GEMM LDS as scratch
            int tx = tid & 31, ty = tid >> 5;
            __syncthreads();   // protect Ls reuse across loop iterations
#pragma unroll
            for (int r = 0; r < 4; ++r) {
                int k = ty + r * 8;
                Ls[tx][k] = f2bf(W[(size_t)(k0 + k) * ldw + n0 + tx]);
            }
            __syncthreads();
#pragma unroll
            for (int r = 0; r < 4; ++r) {
                int n = ty + r * 8;
                outp[(size_t)(n0 + n) * 768 + k0 + tx] = Ls[n][tx];
            }
        }
    }
    gridbar(p.bar + 0);

    // ================= Phase B: y2[1024][2816] = [tanh(pooled@cw1+b1) | q | k | v] ==========
    {
        int bid = blockIdx.x;
        int sw = (bid & 7) * 88 + (bid >> 3);   // bijective XCD swizzle (704 = 8*88)
        int ct = sw >> 4;          // 0..43
        int rt = sw & 15;          // 0..15
        int ccol0 = ct * 64, row0 = rt * 64;
        int act = (ccol0 < 512);
        f32x4 acc[2][2];
        gemm_tile(p.pooled_bf, p.wcat_t, &As[0][0], &Bs[0][0], row0, ccol0, tid, acc);
        // C/D layout: col=lane&15, row=(lane>>4)*4+reg  [m89-verified]
#pragma unroll
        for (int tm = 0; tm < 2; ++tm)
#pragma unroll
            for (int tn = 0; tn < 2; ++tn)
#pragma unroll
                for (int reg = 0; reg < 4; ++reg) {
                    int rr = row0 + wm + tm * 16 + q * 4 + reg;
                    int cc = ccol0 + wn + tn * 16 + l15;
                    float v = acc[tm][tn][reg];
                    if (act) v = ftanh(v + p.comp_b1[cc]);
                    p.y2[(size_t)rr * 2816 + cc] = v;
                }
    }
    gridbar(p.bar + 1);

    // ================= Phase C: attention + residual + LayerNorm (one wave per (b,n)) ==========
    if (blockIdx.x < 256) {
        int l = lane;
        int gw = blockIdx.x * 4 + w;          // 0..1023
        int b = gw >> 4, n = gw & 15;
        const float* qrow = p.y2 + (size_t)(b * 16 + n) * 2816 + 512;
        float qv[12];
#pragma unroll
        for (int u = 0; u < 12; ++u) qv[u] = qrow[l + 64 * u];

        float s[16];
#pragma unroll
        for (int m = 0; m < 16; ++m) {
            const float* krow = p.y2 + (size_t)(b * 16 + m) * 2816 + 1280;
            float pv = 0.f;
#pragma unroll
            for (int u = 0; u < 12; ++u) pv += qv[u] * krow[l + 64 * u];
#pragma unroll
            for (int off = 32; off >= 1; off >>= 1) pv += __shfl_xor(pv, off);
            s[m] = pv * 0.03608439182435161f;   // 1/sqrt(768)
        }
        float mx = s[0];
#pragma unroll
        for (int m = 1; m < 16; ++m) mx = fmaxf(mx, s[m]);
        float den = 0.f;
#pragma unroll
        for (int m = 0; m < 16; ++m) { s[m] = __expf(s[m] - mx); den += s[m]; }
        float inv = 1.0f / den;

        float acc[12];
#pragma unroll
        for (int u = 0; u < 12; ++u) acc[u] = 0.f;
#pragma unroll
        for (int m = 0; m < 16; ++m) {
            const float* vrow = p.y2 + (size_t)(b * 16 + m) * 2816 + 2048;
            float pm = s[m] * inv;
#pragma unroll
            for (int u = 0; u < 12; ++u) acc[u] += pm * vrow[l + 64 * u];
        }

        int row = b * 16 + n;
        const float* prow = p.pooled + (size_t)row * HH;
        float xv[12];
        float ssum = 0.f, ssq = 0.f;
#pragma unroll
        for (int u = 0; u < 12; ++u) {
            float v = prow[l + 64 * u] + acc[u];
            xv[u] = v;
            ssum += v;
            ssq += v * v;
        }
#pragma unroll
        for (int off = 32; off >= 1; off >>= 1) {
            ssum += __shfl_xor(ssum, off);
            ssq += __shfl_xor(ssq, off);
        }
        float mu = ssum * (1.0f / 768.0f);
        float var = ssq * (1.0f / 768.0f) - mu * mu;
        float rs = rsqrtf(var + 1e-5f);
        u16* xrow_bf = p.x_bf + (size_t)row * HH;
#pragma unroll
        for (int u = 0; u < 12; ++u) {
            int h = l + 64 * u;
            xrow_bf[h] = f2bf((xv[u] - mu) * rs * p.ln_g[h] + p.ln_b[h]);
        }
    }
    gridbar(p.bar + 2);

    // ================= Phase D: Z[1024][1024] = x @ [W_top | W_bot] ==========
    if (blockIdx.x < 256) {
        int bid = blockIdx.x;
        int sw = (bid & 7) * 32 + (bid >> 3);   // bijective (256 = 8*32)
        int ct = sw >> 4;          // 0..15
        int rt = sw & 15;          // 0..15
        int ccol0 = ct * 64, row0 = rt * 64;
        f32x4 acc[2][2];
        gemm_tile(p.x_bf, p.relw_t, &As[0][0], &Bs[0][0], row0, ccol0, tid, acc);
#pragma unroll
        for (int tm = 0; tm < 2; ++tm)
#pragma unroll
            for (int tn = 0; tn < 2; ++tn)
#pragma unroll
                for (int reg = 0; reg < 4; ++reg) {
                    int rr = row0 + wm + tm * 16 + q * 4 + reg;
                    int cc = ccol0 + wn + tn * 16 + l15;
                    p.Z[(size_t)rr * 1024 + cc] = acc[tm][tn][reg];
                }
    }
    gridbar(p.bar + 3);

    // ================= Phase E: heads — units [0,3840) rel, [3840,4096) comp ==========
    for (int u = blockIdx.x; u < 4096; u += NBLK) {
        if (u < 3840) {
            int row = u * 4 + w;   // 0..15359
            int b = row / PP;
            int pp = row - b * PP;
            int i = pp / 15;
            int jj = pp - i * 15;
            int j = jj + (jj >= i ? 1 : 0);
            const float* z1 = p.Z + ((size_t)(b * 16 + i)) * 1024;
            const float* z2 = p.Z + ((size_t)(b * 16 + j)) * 1024 + 512;
            float a0 = 0.f, a1 = 0.f, a2 = 0.f;
#pragma unroll
            for (int t = 0; t < 2; ++t) {
                int c = (lane + (t << 6)) << 2;      // 4-float chunk base
                float4 zv1 = *(const float4*)(z1 + c);
                float4 zv2 = *(const float4*)(z2 + c);
                float4 bv  = *(const float4*)(p.rel_b1 + c);
                float4 w0 = *(const float4*)(p.rel_w2 + c * 3);
                float4 w1 = *(const float4*)(p.rel_w2 + c * 3 + 4);
                float4 w2 = *(const float4*)(p.rel_w2 + c * 3 + 8);
                float fw[12] = {w0.x, w0.y, w0.z, w0.w, w1.x, w1.y, w1.z, w1.w, w2.x, w2.y, w2.z, w2.w};
                float h0 = ftanh(zv1.x + zv2.x + bv.x);
                float h1 = ftanh(zv1.y + zv2.y + bv.y);
                float h2 = ftanh(zv1.z + zv2.z + bv.z);
                float h3 = ftanh(zv1.w + zv2.w + bv.w);
                a0 += h0 * fw[0] + h1 * fw[3] + h2 * fw[6] + h3 * fw[9];
                a1 += h0 * fw[1] + h1 * fw[4] + h2 * fw[7] + h3 * fw[10];
                a2 += h0 * fw[2] + h1 * fw[5] + h2 * fw[8] + h3 * fw[11];
            }
#pragma unroll
            for (int off = 32; off >= 1; off >>= 1) {
                a0 += __shfl_down(a0, off);
                a1 += __shfl_down(a1, off);
                a2 += __shfl_down(a2, off);
            }
            if (lane == 0) {
                float l0 = a0 + p.rel_b2[0];
                float l1 = a1 + p.rel_b2[1];
                float l2 = a2 + p.rel_b2[2];
                float mxv = fmaxf(l0, fmaxf(l1, l2));
                float se = __expf(l0 - mxv) + __expf(l1 - mxv) + __expf(l2 - mxv);
                float lse = __logf(se) + mxv;
                int g = p.rels[row];
                float lg = (g == 0) ? l0 : ((g == 1) ? l1 : l2);
                red[w] = lse - lg;
                float* o = p.out + 5120 + (size_t)row * 3;
                o[0] = l0; o[1] = l1; o[2] = l2;
            }
            __syncthreads();
            if (tid == 0) p.rel_p[u] = red[0] + red[1] + red[2] + red[3];
            __syncthreads();
        } else {
            int row = (u - 3840) * 4 + w;  // 0..1023
            const float* hrow = p.y2 + (size_t)row * 2816;
            float acc[CCOMP] = {0.f, 0.f, 0.f, 0.f, 0.f};
#pragma unroll
            for (int t = 0; t < 2; ++t) {
                int c = (lane + (t << 6)) << 2;
                float4 hv = *(const float4*)(hrow + c);
                float4 g0 = *(const float4*)(p.comp_w2 + c * 5);
                float4 g1 = *(const float4*)(p.comp_w2 + c * 5 + 4);
                float4 g2 = *(const float4*)(p.comp_w2 + c * 5 + 8);
                float4 g3 = *(const float4*)(p.comp_w2 + c * 5 + 12);
                float4 g4 = *(const float4*)(p.comp_w2 + c * 5 + 16);
                float fw[20] = {g0.x, g0.y, g0.z, g0.w, g1.x, g1.y, g1.z, g1.w,
                                g2.x, g2.y, g2.z, g2.w, g3.x, g3.y, g3.z, g3.w,
                                g4.x, g4.y, g4.z, g4.w};
                float hh[4] = {hv.x, hv.y, hv.z, hv.w};
#pragma unroll
                for (int jj = 0; jj < 4; ++jj)
#pragma unroll
                    for (int cc = 0; cc < CCOMP; ++cc) acc[cc] += hh[jj] * fw[5 * jj + cc];
            }
#pragma unroll
            for (int cc = 0; cc < CCOMP; ++cc)
#pragma unroll
                for (int off = 32; off >= 1; off >>= 1) acc[cc] += __shfl_down(acc[cc], off);
            if (lane == 0) {
                float lg[CCOMP];
                float mxv = -1e30f;
#pragma unroll
                for (int cc = 0; cc < CCOMP; ++cc) { lg[cc] = acc[cc] + p.comp_b2[cc]; mxv = fmaxf(mxv, lg[cc]); }
                float se = 0.f;
#pragma unroll
                for (int cc = 0; cc < CCOMP; ++cc) se += __expf(lg[cc] - mxv);
                float lse = __logf(se) + mxv;
                red[w] = lse - lg[p.comps[row]];
#pragma unroll
                for (int cc = 0; cc < CCOMP; ++cc) p.out[row * CCOMP + cc] = lg[cc];
            }
            __syncthreads();
            if (tid == 0) p.comp_p[u - 3840] = red[0] + red[1] + red[2] + red[3];
            __syncthreads();
        }
    }
    gridbar(p.bar + 4);

    // ================= Phase F: final loss reduction ==========
    if (blockIdx.x == 0) {
        float sc = p.comp_p[tid];
        float sr = 0.f;
#pragma unroll
        for (int k = 0; k < 15; ++k) sr += p.rel_p[tid + k * 256];
#pragma unroll
        for (int off = 32; off >= 1; off >>= 1) {
            sc += __shfl_down(sc, off);
            sr += __shfl_down(sr, off);
        }
        if (lane == 0) { red[w] = sc; red[4 + w] = sr; }
        __syncthreads();
        if (tid == 0) {
            p.out[51200] = (red[0] + red[1] + red[2] + red[3]) * (1.0f / 1024.0f);
            p.out[51201] = (red[4] + red[5] + red[6] + red[7]) * (1.0f / 15360.0f);
        }
    }
}

extern "C" void kernel_launch(void* const* d_in, const int* in_sizes, int n_in,
                              void* d_out, int out_size, void* d_ws, size_t ws_size,
                              hipStream_t stream) {
    float* ws = (float*)d_ws;

    Params p;
    p.lhs     = (const float*)d_in[0];
    p.starts  = (const int*)d_in[1];
    p.lens    = (const int*)d_in[2];
    p.comps   = (const int*)d_in[3];
    p.rels    = (const int*)d_in[4];
    p.comp_w1 = (const float*)d_in[5];
    p.comp_b1 = (const float*)d_in[6];
    p.comp_w2 = (const float*)d_in[7];
    p.comp_b2 = (const float*)d_in[8];
    p.wq      = (const float*)d_in[9];
    p.wk      = (const float*)d_in[10];
    p.wv      = (const float*)d_in[11];
    p.ln_g    = (const float*)d_in[12];
    p.ln_b    = (const float*)d_in[13];
    p.rel_w1  = (const float*)d_in[14];
    p.rel_b1  = (const float*)d_in[15];
    p.rel_w2  = (const float*)d_in[16];
    p.rel_b2  = (const float*)d_in[17];
    p.out     = (float*)d_out;

    p.pooled = ws;                            // 1024*768
    p.y2     = p.pooled + 786432;             // 1024*2816
    p.Z      = p.y2 + 2883584;                // 1024*1024
    p.comp_p = p.Z + 1048576;                 // 256
    p.rel_p  = p.comp_p + 256;                // 3840
    p.pooled_bf = (u16*)(p.rel_p + 3840);     // 786432 u16
    p.x_bf      = p.pooled_bf + 786432;       // 786432
    p.wcat_t    = p.x_bf + 786432;            // 2816*768
    p.relw_t    = p.wcat_t + 2162688;         // 1024*768
    p.bar       = (unsigned int*)(ws + 8 * 1024 * 1024);   // +32MB, past all buffers

    hipMemsetAsync(p.bar, 0, 64, stream);
    fused_kernel<<<NBLK, 256, 0, stream>>>(p);
}

// Round 7
// 767.366 us; speedup vs baseline: 2.0628x; 2.0628x over previous
//
#include <hip/hip_runtime.h>

#define SS 512
#define HH 768
#define PP 240
#define CCOMP 5
#define NBLK 704

typedef unsigned short u16;
typedef __attribute__((ext_vector_type(8))) short bf16x8;   // 8 bf16 in 4 VGPRs
typedef __attribute__((ext_vector_type(4))) float f32x4;

__device__ __forceinline__ u16 f2bf(float f) {
    union { float f; unsigned int i; } v; v.f = f;
    unsigned int x = v.i;
    unsigned int lsb = (x >> 16) & 1u;
    x += 0x7fffu + lsb;
    return (u16)(x >> 16);
}

__device__ __forceinline__ float ftanh(float x) {
    float xc = fminf(fmaxf(x, -15.f), 15.f);
    float e = __expf(2.f * xc);
    return (e - 1.f) / (e + 1.f);
}

// async global->LDS, 16B per lane; dest = wave-uniform base + lane*16
__device__ __forceinline__ void gl_lds16(const void* g, void* l) {
    __builtin_amdgcn_global_load_lds(
        (const __attribute__((address_space(1))) unsigned int*)g,
        (__attribute__((address_space(3))) unsigned int*)l, 16, 0, 0);
}

// software grid barrier.
// Ordering semantics PROVEN on HW in round 3 (acquire-poll version passed):
//   arrive = RELEASE fetch_add; poll = ACQUIRE loads; both agent scope.
// Round 3's cost problem: polling every ~0.05us from ~700 blocks = 14000
// buffer_inv/us (each flushes an XCD L2) -> all phases ran cold (6x slower).
// Round 4/5 lesson: RELAXED polling never observes remote arrivals -> hang.
// Fix: keep acquire polls, throttle ~80x (4 fast polls, then ~1.7us sleeps).
// s_sleep arg must be a LITERAL (round-6 compile fail) -> branch to constants.
// Bailout cap turns any residual hang into a numeric fail, not a container kill.
__device__ __forceinline__ void gridbar(unsigned int* c) {
    __syncthreads();
    if (threadIdx.x == 0) {
        __hip_atomic_fetch_add(c, 1u, __ATOMIC_RELEASE, __HIP_MEMORY_SCOPE_AGENT);
        for (long it = 0; it < 2000000; ++it) {
            if (__hip_atomic_load(c, __ATOMIC_ACQUIRE, __HIP_MEMORY_SCOPE_AGENT) >= NBLK)
                break;
            if (it < 4) __builtin_amdgcn_s_sleep(4);
            else        __builtin_amdgcn_s_sleep(64);
        }
    }
    __syncthreads();
}

struct Params {
    const float* lhs; const int* starts; const int* lens; const int* comps; const int* rels;
    const float* comp_w1; const float* comp_b1; const float* comp_w2; const float* comp_b2;
    const float* wq; const float* wk; const float* wv;
    const float* ln_g; const float* ln_b;
    const float* rel_w1; const float* rel_b1; const float* rel_w2; const float* rel_b2;
    float* out;
    float* pooled; float* y2; float* Z; float* comp_p; float* rel_p;
    u16* pooled_bf; u16* x_bf; u16* wcat_t; u16* relw_t;
    unsigned int* bar;
};

// 64x64-tile bf16 MFMA GEMM body: global_load_lds staging, XOR swizzle, 1-barrier dbuf.
// K = 768 fixed. A rows at Abase (row-major K-contig), B rows at Bbase (row-major K-contig).
__device__ __forceinline__ void gemm_tile(
    const u16* Abase, const u16* Bbase, u16* AsR, u16* BsR,
    int row0, int ccol0, int tid, f32x4 acc[2][2]) {
    int lane = tid & 63, w = tid >> 6;
    int q = lane >> 4, l15 = lane & 15;
    int wm = (w & 1) * 32, wn = (w >> 1) * 32;

    int srow = w * 8 + (lane >> 3);               // 0..31 (second issue adds +32)
    int sxs = ((lane & 7) * 16) ^ ((srow & 7) << 4);
    const char* gA0 = (const char*)(Abase + (size_t)(row0 + srow) * 768) + sxs;
    const char* gA1 = gA0 + (size_t)32 * 768 * 2;
    const char* gB0 = (const char*)(Bbase + (size_t)(ccol0 + srow) * 768) + sxs;
    const char* gB1 = gB0 + (size_t)32 * 768 * 2;
    char* lA = (char*)AsR + w * 1024;
    char* lB = (char*)BsR + w * 1024;

#pragma unroll
    for (int i = 0; i < 2; ++i)
#pragma unroll
        for (int j = 0; j < 2; ++j) acc[i][j] = (f32x4){0.f, 0.f, 0.f, 0.f};

#define STAGE_T(BUF, KB) do { \
        gl_lds16(gA0 + (KB), lA + (BUF) * 8192); \
        gl_lds16(gA1 + (KB), lA + (BUF) * 8192 + 4096); \
        gl_lds16(gB0 + (KB), lB + (BUF) * 8192); \
        gl_lds16(gB1 + (KB), lB + (BUF) * 8192 + 4096); \
    } while (0)

    STAGE_T(0, 0);
    asm volatile("s_waitcnt vmcnt(0)" ::: "memory");
    __syncthreads();
    int cur = 0;
    for (int t = 0; t < 12; ++t) {
        if (t < 11) STAGE_T(cur ^ 1, (t + 1) * 128);
        const char* Ab = (const char*)AsR + cur * 8192;
        const char* Bb = (const char*)BsR + cur * 8192;
#pragma unroll
        for (int ks = 0; ks < 2; ++ks) {
            int o = ks * 64 + q * 16;
            int Ra0 = wm + l15, Ra1 = wm + 16 + l15;
            int Rb0 = wn + l15, Rb1 = wn + 16 + l15;
            bf16x8 a0 = *(const bf16x8*)(Ab + Ra0 * 128 + (o ^ ((Ra0 & 7) << 4)));
            bf16x8 a1 = *(const bf16x8*)(Ab + Ra1 * 128 + (o ^ ((Ra1 & 7) << 4)));
            bf16x8 b0 = *(const bf16x8*)(Bb + Rb0 * 128 + (o ^ ((Rb0 & 7) << 4)));
            bf16x8 b1 = *(const bf16x8*)(Bb + Rb1 * 128 + (o ^ ((Rb1 & 7) << 4)));
            acc[0][0] = __builtin_amdgcn_mfma_f32_16x16x32_bf16(a0, b0, acc[0][0], 0, 0, 0);
            acc[0][1] = __builtin_amdgcn_mfma_f32_16x16x32_bf16(a0, b1, acc[0][1], 0, 0, 0);
            acc[1][0] = __builtin_amdgcn_mfma_f32_16x16x32_bf16(a1, b0, acc[1][0], 0, 0, 0);
            acc[1][1] = __builtin_amdgcn_mfma_f32_16x16x32_bf16(a1, b1, acc[1][1], 0, 0, 0);
        }
        asm volatile("s_waitcnt vmcnt(0)" ::: "memory");
        __syncthreads();
        cur ^= 1;
    }
#undef STAGE_T
}

__global__ __launch_bounds__(256, 4) void fused_kernel(Params p) {
    __shared__ u16 As[2][4096];
    __shared__ u16 Bs[2][4096];
    __shared__ float red[8];
    int tid = threadIdx.x;
    int lane = tid & 63, w = tid >> 6;
    int q = lane >> 4, l15 = lane & 15;
    int wm = (w & 1) * 32, wn = (w >> 1) * 32;

    // ================= Phase A: span pooling (units 0..1023) + weight prep (1024..3903) ==========
    for (int u = blockIdx.x; u < 3904; u += NBLK) {
        if (u < 1024) {
            if (tid < 192) {
                int st = p.starts[u];
                int ln = p.lens[u];
                int b = u >> 4;
                const float4* base = (const float4*)(p.lhs + ((size_t)b * SS + st) * HH);
                float4 a = {0.f, 0.f, 0.f, 0.f};
                for (int s = 0; s <= ln; ++s) {
                    float4 v = base[s * 192 + tid];
                    a.x += v.x; a.y += v.y; a.z += v.z; a.w += v.w;
                }
                float inv = 1.0f / (float)(ln + 1);
                a.x *= inv; a.y *= inv; a.z *= inv; a.w *= inv;
                *(float4*)(p.pooled + (size_t)u * HH + tid * 4) = a;
                ushort4 ub = { f2bf(a.x), f2bf(a.y), f2bf(a.z), f2bf(a.w) };
                *(ushort4*)(p.pooled_bf + (size_t)u * HH + tid * 4) = ub;
            }
        } else {
            int blk = u - 1024;
            const float* W; int ldw, nt; u16* outp;
            if (blk < 384)        {             W = p.comp_w1; ldw = 512; nt = 16; outp = p.wcat_t; }
            else if (blk < 960)   { blk -= 384; W = p.wq;  ldw = 768; nt = 24; outp = p.wcat_t + (size_t)512 * 768; }
            else if (blk < 1536)  { blk -= 960; W = p.wk;  ldw = 768; nt = 24; outp = p.wcat_t + (size_t)1280 * 768; }
            else if (blk < 2112)  { blk -= 1536; W = p.wv; ldw = 768; nt = 24; outp = p.wcat_t + (size_t)2048 * 768; }
            else if (blk < 2496)  { blk -= 2112; W = p.rel_w1; ldw = 512; nt = 16; outp = p.relw_t; }
            else                  { blk -= 2496; W = p.rel_w1 + (size_t)768 * 512; ldw = 512; nt = 16; outp = p.relw_t + (size_t)512 * 768; }
            int tk = blk / nt, tn = blk % nt;
            int k0 = tk * 32, n0 = tn * 32;
            u16 (*Ls)[36] = (u16(*)[36])As;   // alias GEMM LDS as scratch
            int tx = tid & 31, ty = tid >> 5;
            __syncthreads();   // protect Ls reuse across loop iterations
#pragma unroll
            for (int r = 0; r < 4; ++r) {
                int k = ty + r * 8;
                Ls[tx][k] = f2bf(W[(size_t)(k0 + k) * ldw + n0 + tx]);
            }
            __syncthreads();
#pragma unroll
            for (int r = 0; r < 4; ++r) {
                int n = ty + r * 8;
                outp[(size_t)(n0 + n) * 768 + k0 + tx] = Ls[n][tx];
            }
        }
    }
    gridbar(p.bar + 0);

    // ================= Phase B: y2[1024][2816] = [tanh(pooled@cw1+b1) | q | k | v] ==========
    {
        int bid = blockIdx.x;
        int sw = (bid & 7) * 88 + (bid >> 3);   // bijective XCD swizzle (704 = 8*88)
        int ct = sw >> 4;          // 0..43
        int rt = sw & 15;          // 0..15
        int ccol0 = ct * 64, row0 = rt * 64;
        int act = (ccol0 < 512);
        f32x4 acc[2][2];
        gemm_tile(p.pooled_bf, p.wcat_t, &As[0][0], &Bs[0][0], row0, ccol0, tid, acc);
        // C/D layout: col=lane&15, row=(lane>>4)*4+reg  [m89-verified]
#pragma unroll
        for (int tm = 0; tm < 2; ++tm)
#pragma unroll
            for (int tn = 0; tn < 2; ++tn)
#pragma unroll
                for (int reg = 0; reg < 4; ++reg) {
                    int rr = row0 + wm + tm * 16 + q * 4 + reg;
                    int cc = ccol0 + wn + tn * 16 + l15;
                    float v = acc[tm][tn][reg];
                    if (act) v = ftanh(v + p.comp_b1[cc]);
                    p.y2[(size_t)rr * 2816 + cc] = v;
                }
    }
    gridbar(p.bar + 1);

    // ================= Phase C: attention + residual + LayerNorm (one wave per (b,n) row) ==========
    // rows spread over ALL 704 blocks (waves 0,1) to halve phase skew: row = w*704 + bid
    {
        int gw = w * NBLK + blockIdx.x;
        if (gw < 1024) {
            int l = lane;
            int b = gw >> 4, n = gw & 15;
            const float* qrow = p.y2 + (size_t)(b * 16 + n) * 2816 + 512;
            float qv[12];
#pragma unroll
            for (int u = 0; u < 12; ++u) qv[u] = qrow[l + 64 * u];

            float s[16];
#pragma unroll
            for (int m = 0; m < 16; ++m) {
                const float* krow = p.y2 + (size_t)(b * 16 + m) * 2816 + 1280;
                float pv = 0.f;
#pragma unroll
                for (int u = 0; u < 12; ++u) pv += qv[u] * krow[l + 64 * u];
#pragma unroll
                for (int off = 32; off >= 1; off >>= 1) pv += __shfl_xor(pv, off);
                s[m] = pv * 0.03608439182435161f;   // 1/sqrt(768)
            }
            float mx = s[0];
#pragma unroll
            for (int m = 1; m < 16; ++m) mx = fmaxf(mx, s[m]);
            float den = 0.f;
#pragma unroll
            for (int m = 0; m < 16; ++m) { s[m] = __expf(s[m] - mx); den += s[m]; }
            float inv = 1.0f / den;

            float acc[12];
#pragma unroll
            for (int u = 0; u < 12; ++u) acc[u] = 0.f;
#pragma unroll
            for (int m = 0; m < 16; ++m) {
                const float* vrow = p.y2 + (size_t)(b * 16 + m) * 2816 + 2048;
                float pm = s[m] * inv;
#pragma unroll
                for (int u = 0; u < 12; ++u) acc[u] += pm * vrow[l + 64 * u];
            }

            int row = b * 16 + n;
            const float* prow = p.pooled + (size_t)row * HH;
            float xv[12];
            float ssum = 0.f, ssq = 0.f;
#pragma unroll
            for (int u = 0; u < 12; ++u) {
                float v = prow[l + 64 * u] + acc[u];
                xv[u] = v;
                ssum += v;
                ssq += v * v;
            }
#pragma unroll
            for (int off = 32; off >= 1; off >>= 1) {
                ssum += __shfl_xor(ssum, off);
                ssq += __shfl_xor(ssq, off);
            }
            float mu = ssum * (1.0f / 768.0f);
            float var = ssq * (1.0f / 768.0f) - mu * mu;
            float rs = rsqrtf(var + 1e-5f);
            u16* xrow_bf = p.x_bf + (size_t)row * HH;
#pragma unroll
            for (int u = 0; u < 12; ++u) {
                int h = l + 64 * u;
                xrow_bf[h] = f2bf((xv[u] - mu) * rs * p.ln_g[h] + p.ln_b[h]);
            }
        }
    }
    gridbar(p.bar + 2);

    // ================= Phase D: Z[1024][1024] = x @ [W_top | W_bot] ==========
    if (blockIdx.x < 256) {
        int bid = blockIdx.x;
        int sw = (bid & 7) * 32 + (bid >> 3);   // bijective (256 = 8*32)
        int ct = sw >> 4;          // 0..15
        int rt = sw & 15;          // 0..15
        int ccol0 = ct * 64, row0 = rt * 64;
        f32x4 acc[2][2];
        gemm_tile(p.x_bf, p.relw_t, &As[0][0], &Bs[0][0], row0, ccol0, tid, acc);
#pragma unroll
        for (int tm = 0; tm < 2; ++tm)
#pragma unroll
            for (int tn = 0; tn < 2; ++tn)
#pragma unroll
                for (int reg = 0; reg < 4; ++reg) {
                    int rr = row0 + wm + tm * 16 + q * 4 + reg;
                    int cc = ccol0 + wn + tn * 16 + l15;
                    p.Z[(size_t)rr * 1024 + cc] = acc[tm][tn][reg];
                }
    }
    gridbar(p.bar + 3);

    // ================= Phase E: heads — units [0,3840) rel, [3840,4096) comp ==========
    for (int u = blockIdx.x; u < 4096; u += NBLK) {
        if (u < 3840) {
            int row = u * 4 + w;   // 0..15359
            int b = row / PP;
            int pp = row - b * PP;
            int i = pp / 15;
            int jj = pp - i * 15;
            int j = jj + (jj >= i ? 1 : 0);
            const float* z1 = p.Z + ((size_t)(b * 16 + i)) * 1024;
            const float* z2 = p.Z + ((size_t)(b * 16 + j)) * 1024 + 512;
            float a0 = 0.f, a1 = 0.f, a2 = 0.f;
#pragma unroll
            for (int t = 0; t < 2; ++t) {
                int c = (lane + (t << 6)) << 2;      // 4-float chunk base
                float4 zv1 = *(const float4*)(z1 + c);
                float4 zv2 = *(const float4*)(z2 + c);
                float4 bv  = *(const float4*)(p.rel_b1 + c);
                float4 w0 = *(const float4*)(p.rel_w2 + c * 3);
                float4 w1 = *(const float4*)(p.rel_w2 + c * 3 + 4);
                float4 w2 = *(const float4*)(p.rel_w2 + c * 3 + 8);
                float fw[12] = {w0.x, w0.y, w0.z, w0.w, w1.x, w1.y, w1.z, w1.w, w2.x, w2.y, w2.z, w2.w};
                float h0 = ftanh(zv1.x + zv2.x + bv.x);
                float h1 = ftanh(zv1.y + zv2.y + bv.y);
                float h2 = ftanh(zv1.z + zv2.z + bv.z);
                float h3 = ftanh(zv1.w + zv2.w + bv.w);
                a0 += h0 * fw[0] + h1 * fw[3] + h2 * fw[6] + h3 * fw[9];
                a1 += h0 * fw[1] + h1 * fw[4] + h2 * fw[7] + h3 * fw[10];
                a2 += h0 * fw[2] + h1 * fw[5] + h2 * fw[8] + h3 * fw[11];
            }
#pragma unroll
            for (int off = 32; off >= 1; off >>= 1) {
                a0 += __shfl_down(a0, off);
                a1 += __shfl_down(a1, off);
                a2 += __shfl_down(a2, off);
            }
            if (lane == 0) {
                float l0 = a0 + p.rel_b2[0];
                float l1 = a1 + p.rel_b2[1];
                float l2 = a2 + p.rel_b2[2];
                float mxv = fmaxf(l0, fmaxf(l1, l2));
                float se = __expf(l0 - mxv) + __expf(l1 - mxv) + __expf(l2 - mxv);
                float lse = __logf(se) + mxv;
                int g = p.rels[row];
                float lg = (g == 0) ? l0 : ((g == 1) ? l1 : l2);
                red[w] = lse - lg;
                float* o = p.out + 5120 + (size_t)row * 3;
                o[0] = l0; o[1] = l1; o[2] = l2;
            }
            __syncthreads();
            if (tid == 0) p.rel_p[u] = red[0] + red[1] + red[2] + red[3];
            __syncthreads();
        } else {
            int row = (u - 3840) * 4 + w;  // 0..1023
            const float* hrow = p.y2 + (size_t)row * 2816;
            float acc[CCOMP] = {0.f, 0.f, 0.f, 0.f, 0.f};
#pragma unroll
            for (int t = 0; t < 2; ++t) {
                int c = (lane + (t << 6)) << 2;
                float4 hv = *(const float4*)(hrow + c);
                float4 g0 = *(const float4*)(p.comp_w2 + c * 5);
                float4 g1 = *(const float4*)(p.comp_w2 + c * 5 + 4);
                float4 g2 = *(const float4*)(p.comp_w2 + c * 5 + 8);
                float4 g3 = *(const float4*)(p.comp_w2 + c * 5 + 12);
                float4 g4 = *(const float4*)(p.comp_w2 + c * 5 + 16);
                float fw[20] = {g0.x, g0.y, g0.z, g0.w, g1.x, g1.y, g1.z, g1.w,
                                g2.x, g2.y, g2.z, g2.w, g3.x, g3.y, g3.z, g3.w,
                                g4.x, g4.y, g4.z, g4.w};
                float hh[4] = {hv.x, hv.y, hv.z, hv.w};
#pragma unroll
                for (int jj = 0; jj < 4; ++jj)
#pragma unroll
                    for (int cc = 0; cc < CCOMP; ++cc) acc[cc] += hh[jj] * fw[5 * jj + cc];
            }
#pragma unroll
            for (int cc = 0; cc < CCOMP; ++cc)
#pragma unroll
                for (int off = 32; off >= 1; off >>= 1) acc[cc] += __shfl_down(acc[cc], off);
            if (lane == 0) {
                float lg[CCOMP];
                float mxv = -1e30f;
#pragma unroll
                for (int cc = 0; cc < CCOMP; ++cc) { lg[cc] = acc[cc] + p.comp_b2[cc]; mxv = fmaxf(mxv, lg[cc]); }
                float se = 0.f;
#pragma unroll
                for (int cc = 0; cc < CCOMP; ++cc) se += __expf(lg[cc] - mxv);
                float lse = __logf(se) + mxv;
                red[w] = lse - lg[p.comps[row]];
#pragma unroll
                for (int cc = 0; cc < CCOMP; ++cc) p.out[row * CCOMP + cc] = lg[cc];
            }
            __syncthreads();
            if (tid == 0) p.comp_p[u - 3840] = red[0] + red[1] + red[2] + red[3];
            __syncthreads();
        }
    }
    gridbar(p.bar + 4);

    // ================= Phase F: final loss reduction ==========
    if (blockIdx.x == 0) {
        float sc = p.comp_p[tid];
        float sr = 0.f;
#pragma unroll
        for (int k = 0; k < 15; ++k) sr += p.rel_p[tid + k * 256];
#pragma unroll
        for (int off = 32; off >= 1; off >>= 1) {
            sc += __shfl_down(sc, off);
            sr += __shfl_down(sr, off);
        }
        if (lane == 0) { red[w] = sc; red[4 + w] = sr; }
        __syncthreads();
        if (tid == 0) {
            p.out[51200] = (red[0] + red[1] + red[2] + red[3]) * (1.0f / 1024.0f);
            p.out[51201] = (red[4] + red[5] + red[6] + red[7]) * (1.0f / 15360.0f);
        }
    }
}

extern "C" void kernel_launch(void* const* d_in, const int* in_sizes, int n_in,
                              void* d_out, int out_size, void* d_ws, size_t ws_size,
                              hipStream_t stream) {
    float* ws = (float*)d_ws;

    Params p;
    p.lhs     = (const float*)d_in[0];
    p.starts  = (const int*)d_in[1];
    p.lens    = (const int*)d_in[2];
    p.comps   = (const int*)d_in[3];
    p.rels    = (const int*)d_in[4];
    p.comp_w1 = (const float*)d_in[5];
    p.comp_b1 = (const float*)d_in[6];
    p.comp_w2 = (const float*)d_in[7];
    p.comp_b2 = (const float*)d_in[8];
    p.wq      = (const float*)d_in[9];
    p.wk      = (const float*)d_in[10];
    p.wv      = (const float*)d_in[11];
    p.ln_g    = (const float*)d_in[12];
    p.ln_b    = (const float*)d_in[13];
    p.rel_w1  = (const float*)d_in[14];
    p.rel_b1  = (const float*)d_in[15];
    p.rel_w2  = (const float*)d_in[16];
    p.rel_b2  = (const float*)d_in[17];
    p.out     = (float*)d_out;

    p.pooled = ws;                            // 1024*768
    p.y2     = p.pooled + 786432;             // 1024*2816
    p.Z      = p.y2 + 2883584;                // 1024*1024
    p.comp_p = p.Z + 1048576;                 // 256
    p.rel_p  = p.comp_p + 256;                // 3840
    p.pooled_bf = (u16*)(p.rel_p + 3840);     // 786432 u16
    p.x_bf      = p.pooled_bf + 786432;       // 786432
    p.wcat_t    = p.x_bf + 786432;            // 2816*768
    p.relw_t    = p.wcat_t + 2162688;         // 1024*768
    p.bar       = (unsigned int*)(ws + 8 * 1024 * 1024);   // +32MB, past all buffers

    (void)hipMemsetAsync(p.bar, 0, 64, stream);
    fused_kernel<<<NBLK, 256, 0, stream>>>(p);
}

// Round 8
// 324.215 us; speedup vs baseline: 4.8822x; 2.3668x over previous
//
#include <hip/hip_runtime.h>

#define SS 512
#define HH 768
#define PP 240
#define CCOMP 5

typedef unsigned short u16;
typedef __attribute__((ext_vector_type(8))) short bf16x8;   // 8 bf16 in 4 VGPRs
typedef __attribute__((ext_vector_type(4))) float f32x4;

__device__ __forceinline__ u16 f2bf(float f) {
    union { float f; unsigned int i; } v; v.f = f;
    unsigned int x = v.i;
    unsigned int lsb = (x >> 16) & 1u;
    x += 0x7fffu + lsb;
    return (u16)(x >> 16);
}

__device__ __forceinline__ float ftanh(float x) {
    float xc = fminf(fmaxf(x, -15.f), 15.f);
    float e = __expf(2.f * xc);
    return (e - 1.f) / (e + 1.f);
}

// async global->LDS, 16B per lane; dest = wave-uniform base + lane*16
__device__ __forceinline__ void gl_lds16(const void* g, void* l) {
    __builtin_amdgcn_global_load_lds(
        (const __attribute__((address_space(1))) unsigned int*)g,
        (__attribute__((address_space(3))) unsigned int*)l, 16, 0, 0);
}

// ---------------- fused: span mean pooling (blocks 0..1023) + weight prep (1024..3903) ----------------
__global__ __launch_bounds__(256) void prep_pool_kernel(
    const float* __restrict__ lhs, const int* __restrict__ starts,
    const int* __restrict__ lens, float* __restrict__ pooled, u16* __restrict__ pooled_bf,
    const float* __restrict__ cw1, const float* __restrict__ wq,
    const float* __restrict__ wk, const float* __restrict__ wv,
    const float* __restrict__ rw1, u16* __restrict__ wcat_t, u16* __restrict__ relw_t) {
    int blk = blockIdx.x;
    int tid = threadIdx.x;
    if (blk < 1024) {
        if (tid >= 192) return;
        int st = starts[blk];
        int ln = lens[blk];
        int b = blk >> 4;
        const float4* base = (const float4*)(lhs + ((size_t)b * SS + st) * HH);
        float4 a = {0.f, 0.f, 0.f, 0.f};
        for (int s = 0; s <= ln; ++s) {
            float4 v = base[s * 192 + tid];
            a.x += v.x; a.y += v.y; a.z += v.z; a.w += v.w;
        }
        float inv = 1.0f / (float)(ln + 1);
        a.x *= inv; a.y *= inv; a.z *= inv; a.w *= inv;
        *(float4*)(pooled + (size_t)blk * HH + tid * 4) = a;
        ushort4 ub = { f2bf(a.x), f2bf(a.y), f2bf(a.z), f2bf(a.w) };
        *(ushort4*)(pooled_bf + (size_t)blk * HH + tid * 4) = ub;
        return;
    }
    blk -= 1024;
    const float* W; int ldw, nt; u16* outp;
    if (blk < 384)        {             W = cw1; ldw = 512; nt = 16; outp = wcat_t; }
    else if (blk < 960)   { blk -= 384; W = wq;  ldw = 768; nt = 24; outp = wcat_t + (size_t)512 * 768; }
    else if (blk < 1536)  { blk -= 960; W = wk;  ldw = 768; nt = 24; outp = wcat_t + (size_t)1280 * 768; }
    else if (blk < 2112)  { blk -= 1536; W = wv; ldw = 768; nt = 24; outp = wcat_t + (size_t)2048 * 768; }
    else if (blk < 2496)  { blk -= 2112; W = rw1; ldw = 512; nt = 16; outp = relw_t; }
    else                  { blk -= 2496; W = rw1 + (size_t)768 * 512; ldw = 512; nt = 16; outp = relw_t + (size_t)512 * 768; }
    int tk = blk / nt, tn = blk % nt;
    int k0 = tk * 32, n0 = tn * 32;
    __shared__ u16 Ls[32][36];
    int tx = tid & 31, ty = tid >> 5;
#pragma unroll
    for (int r = 0; r < 4; ++r) {
        int k = ty + r * 8;
        Ls[tx][k] = f2bf(W[(size_t)(k0 + k) * ldw + n0 + tx]);
    }
    __syncthreads();
#pragma unroll
    for (int r = 0; r < 4; ++r) {
        int n = ty + r * 8;
        outp[(size_t)(n0 + n) * 768 + k0 + tx] = Ls[n][tx];
    }
}

// 64x64-tile bf16 MFMA GEMM body: global_load_lds staging, XOR swizzle, 1-barrier dbuf.
// K = 768 fixed. Verified numerically in rounds 1/3/7.
__device__ __forceinline__ void gemm_tile(
    const u16* Abase, const u16* Bbase, u16* AsR, u16* BsR,
    int row0, int ccol0, int tid, f32x4 acc[2][2]) {
    int lane = tid & 63, w = tid >> 6;
    int q = lane >> 4, l15 = lane & 15;
    int wm = (w & 1) * 32, wn = (w >> 1) * 32;

    int srow = w * 8 + (lane >> 3);               // 0..31 (second issue adds +32)
    int sxs = ((lane & 7) * 16) ^ ((srow & 7) << 4);
    const char* gA0 = (const char*)(Abase + (size_t)(row0 + srow) * 768) + sxs;
    const char* gA1 = gA0 + (size_t)32 * 768 * 2;
    const char* gB0 = (const char*)(Bbase + (size_t)(ccol0 + srow) * 768) + sxs;
    const char* gB1 = gB0 + (size_t)32 * 768 * 2;
    char* lA = (char*)AsR + w * 1024;
    char* lB = (char*)BsR + w * 1024;

#pragma unroll
    for (int i = 0; i < 2; ++i)
#pragma unroll
        for (int j = 0; j < 2; ++j) acc[i][j] = (f32x4){0.f, 0.f, 0.f, 0.f};

#define STAGE_T(BUF, KB) do { \
        gl_lds16(gA0 + (KB), lA + (BUF) * 8192); \
        gl_lds16(gA1 + (KB), lA + (BUF) * 8192 + 4096); \
        gl_lds16(gB0 + (KB), lB + (BUF) * 8192); \
        gl_lds16(gB1 + (KB), lB + (BUF) * 8192 + 4096); \
    } while (0)

    STAGE_T(0, 0);
    asm volatile("s_waitcnt vmcnt(0)" ::: "memory");
    __syncthreads();
    int cur = 0;
    for (int t = 0; t < 12; ++t) {
        if (t < 11) STAGE_T(cur ^ 1, (t + 1) * 128);
        const char* Ab = (const char*)AsR + cur * 8192;
        const char* Bb = (const char*)BsR + cur * 8192;
#pragma unroll
        for (int ks = 0; ks < 2; ++ks) {
            int o = ks * 64 + q * 16;
            int Ra0 = wm + l15, Ra1 = wm + 16 + l15;
            int Rb0 = wn + l15, Rb1 = wn + 16 + l15;
            bf16x8 a0 = *(const bf16x8*)(Ab + Ra0 * 128 + (o ^ ((Ra0 & 7) << 4)));
            bf16x8 a1 = *(const bf16x8*)(Ab + Ra1 * 128 + (o ^ ((Ra1 & 7) << 4)));
            bf16x8 b0 = *(const bf16x8*)(Bb + Rb0 * 128 + (o ^ ((Rb0 & 7) << 4)));
            bf16x8 b1 = *(const bf16x8*)(Bb + Rb1 * 128 + (o ^ ((Rb1 & 7) << 4)));
            acc[0][0] = __builtin_amdgcn_mfma_f32_16x16x32_bf16(a0, b0, acc[0][0], 0, 0, 0);
            acc[0][1] = __builtin_amdgcn_mfma_f32_16x16x32_bf16(a0, b1, acc[0][1], 0, 0, 0);
            acc[1][0] = __builtin_amdgcn_mfma_f32_16x16x32_bf16(a1, b0, acc[1][0], 0, 0, 0);
            acc[1][1] = __builtin_amdgcn_mfma_f32_16x16x32_bf16(a1, b1, acc[1][1], 0, 0, 0);
        }
        asm volatile("s_waitcnt vmcnt(0)" ::: "memory");
        __syncthreads();
        cur ^= 1;
    }
#undef STAGE_T
}

// ---------------- y2[1024][2816] = [tanh(pooled@cw1+b1) | q | k | v] ----------------
__global__ __launch_bounds__(256) void gemm_pw_kernel(
    const u16* __restrict__ pooled_bf, const u16* __restrict__ wcat_t,
    const float* __restrict__ comp_b1, float* __restrict__ y2) {
    __shared__ u16 As[2][4096];
    __shared__ u16 Bs[2][4096];
    int bid = blockIdx.x;
    int sw = (bid & 7) * 88 + (bid >> 3);   // bijective XCD swizzle (704 = 8*88)
    int ct = sw >> 4, rt = sw & 15;
    int ccol0 = ct * 64, row0 = rt * 64;
    int act = (ccol0 < 512);
    int tid = threadIdx.x;
    int lane = tid & 63, w = tid >> 6;
    int q = lane >> 4, l15 = lane & 15;
    int wm = (w & 1) * 32, wn = (w >> 1) * 32;
    f32x4 acc[2][2];
    gemm_tile(pooled_bf, wcat_t, &As[0][0], &Bs[0][0], row0, ccol0, tid, acc);
    // C/D layout: col=lane&15, row=(lane>>4)*4+reg  [m89-verified]
#pragma unroll
    for (int tm = 0; tm < 2; ++tm)
#pragma unroll
        for (int tn = 0; tn < 2; ++tn)
#pragma unroll
            for (int reg = 0; reg < 4; ++reg) {
                int rr = row0 + wm + tm * 16 + q * 4 + reg;
                int cc = ccol0 + wn + tn * 16 + l15;
                float v = acc[tm][tn][reg];
                if (act) v = ftanh(v + comp_b1[cc]);
                y2[(size_t)rr * 2816 + cc] = v;
            }
}

// ---------------- attention + residual + LayerNorm + comp head (one wave per (b,n)) ----------------
__global__ __launch_bounds__(256) void attn_ln_kernel(
    const float* __restrict__ y2, const float* __restrict__ pooled,
    const float* __restrict__ ln_g, const float* __restrict__ ln_b,
    const float* __restrict__ cw2, const float* __restrict__ cb2,
    const int* __restrict__ comps,
    u16* __restrict__ x_bf, float* __restrict__ out, float* __restrict__ comp_p) {
    int w = threadIdx.x >> 6, l = threadIdx.x & 63;
    int gw = blockIdx.x * 4 + w;          // 0..1023
    int b = gw >> 4, n = gw & 15;
    const float* qrow = y2 + (size_t)(b * 16 + n) * 2816 + 512;
    float qv[12];
#pragma unroll
    for (int u = 0; u < 12; ++u) qv[u] = qrow[l + 64 * u];

    float s[16];
#pragma unroll
    for (int m = 0; m < 16; ++m) {
        const float* krow = y2 + (size_t)(b * 16 + m) * 2816 + 1280;
        float pv = 0.f;
#pragma unroll
        for (int u = 0; u < 12; ++u) pv += qv[u] * krow[l + 64 * u];
#pragma unroll
        for (int off = 32; off >= 1; off >>= 1) pv += __shfl_xor(pv, off);
        s[m] = pv * 0.03608439182435161f;   // 1/sqrt(768)
    }
    float mx = s[0];
#pragma unroll
    for (int m = 1; m < 16; ++m) mx = fmaxf(mx, s[m]);
    float den = 0.f;
#pragma unroll
    for (int m = 0; m < 16; ++m) { s[m] = __expf(s[m] - mx); den += s[m]; }
    float inv = 1.0f / den;

    float acc[12];
#pragma unroll
    for (int u = 0; u < 12; ++u) acc[u] = 0.f;
#pragma unroll
    for (int m = 0; m < 16; ++m) {
        const float* vrow = y2 + (size_t)(b * 16 + m) * 2816 + 2048;
        float pm = s[m] * inv;
#pragma unroll
        for (int u = 0; u < 12; ++u) acc[u] += pm * vrow[l + 64 * u];
    }

    int row = b * 16 + n;
    const float* prow = pooled + (size_t)row * HH;
    float xv[12];
    float ssum = 0.f, ssq = 0.f;
#pragma unroll
    for (int u = 0; u < 12; ++u) {
        float v = prow[l + 64 * u] + acc[u];
        xv[u] = v;
        ssum += v;
        ssq += v * v;
    }
#pragma unroll
    for (int off = 32; off >= 1; off >>= 1) {
        ssum += __shfl_xor(ssum, off);
        ssq += __shfl_xor(ssq, off);
    }
    float mu = ssum * (1.0f / 768.0f);
    float var = ssq * (1.0f / 768.0f) - mu * mu;
    float rs = rsqrtf(var + 1e-5f);
    u16* xrow_bf = x_bf + (size_t)row * HH;
#pragma unroll
    for (int u = 0; u < 12; ++u) {
        int h = l + 64 * u;
        xrow_bf[h] = f2bf((xv[u] - mu) * rs * ln_g[h] + ln_b[h]);
    }

    // ---- comp head for this row (y2[row][0..512] ready since gemm_pw) ----
    const float* hrow = y2 + (size_t)row * 2816;
    float ac[CCOMP] = {0.f, 0.f, 0.f, 0.f, 0.f};
#pragma unroll
    for (int t = 0; t < 2; ++t) {
        int c = (l + (t << 6)) << 2;
        float4 hv = *(const float4*)(hrow + c);
        float4 g0 = *(const float4*)(cw2 + c * 5);
        float4 g1 = *(const float4*)(cw2 + c * 5 + 4);
        float4 g2 = *(const float4*)(cw2 + c * 5 + 8);
        float4 g3 = *(const float4*)(cw2 + c * 5 + 12);
        float4 g4 = *(const float4*)(cw2 + c * 5 + 16);
        float fw[20] = {g0.x, g0.y, g0.z, g0.w, g1.x, g1.y, g1.z, g1.w,
                        g2.x, g2.y, g2.z, g2.w, g3.x, g3.y, g3.z, g3.w,
                        g4.x, g4.y, g4.z, g4.w};
        float hh[4] = {hv.x, hv.y, hv.z, hv.w};
#pragma unroll
        for (int jj = 0; jj < 4; ++jj)
#pragma unroll
            for (int cc = 0; cc < CCOMP; ++cc) ac[cc] += hh[jj] * fw[5 * jj + cc];
    }
#pragma unroll
    for (int cc = 0; cc < CCOMP; ++cc)
#pragma unroll
        for (int off = 32; off >= 1; off >>= 1) ac[cc] += __shfl_down(ac[cc], off);
    if (l == 0) {
        float lg[CCOMP];
        float mxv = -1e30f;
#pragma unroll
        for (int cc = 0; cc < CCOMP; ++cc) { lg[cc] = ac[cc] + cb2[cc]; mxv = fmaxf(mxv, lg[cc]); }
        float se = 0.f;
#pragma unroll
        for (int cc = 0; cc < CCOMP; ++cc) se += __expf(lg[cc] - mxv);
        float lse = __logf(se) + mxv;
        comp_p[row] = lse - lg[comps[row]];
#pragma unroll
        for (int cc = 0; cc < CCOMP; ++cc) out[row * CCOMP + cc] = lg[cc];
    }
}

// ---------------- Z[1024][1024] = x @ [W_top | W_bot] ----------------
__global__ __launch_bounds__(256) void gemm_z_kernel(
    const u16* __restrict__ x_bf, const u16* __restrict__ relw_t, float* __restrict__ Z) {
    __shared__ u16 As[2][4096];
    __shared__ u16 Bs[2][4096];
    int bid = blockIdx.x;
    int sw = (bid & 7) * 32 + (bid >> 3);   // bijective (256 = 8*32)
    int ct = sw >> 4, rt = sw & 15;
    int ccol0 = ct * 64, row0 = rt * 64;
    int tid = threadIdx.x;
    int lane = tid & 63, w = tid >> 6;
    int q = lane >> 4, l15 = lane & 15;
    int wm = (w & 1) * 32, wn = (w >> 1) * 32;
    f32x4 acc[2][2];
    gemm_tile(x_bf, relw_t, &As[0][0], &Bs[0][0], row0, ccol0, tid, acc);
#pragma unroll
    for (int tm = 0; tm < 2; ++tm)
#pragma unroll
        for (int tn = 0; tn < 2; ++tn)
#pragma unroll
            for (int reg = 0; reg < 4; ++reg) {
                int rr = row0 + wm + tm * 16 + q * 4 + reg;
                int cc = ccol0 + wn + tn * 16 + l15;
                Z[(size_t)rr * 1024 + cc] = acc[tm][tn][reg];
            }
}

// ---------------- rel head (3840 blocks) + last-block finalize ----------------
__global__ __launch_bounds__(256) void heads_kernel(
    const float* __restrict__ Z, const float* __restrict__ rb1,
    const float* __restrict__ rw2, const float* __restrict__ rb2,
    const int* __restrict__ rels, const float* __restrict__ comp_p,
    float* __restrict__ out, float* __restrict__ rel_p, unsigned int* __restrict__ cnt) {
    __shared__ float red[8];
    __shared__ int isLast;
    int wave = threadIdx.x >> 6, lane = threadIdx.x & 63;
    int row = blockIdx.x * 4 + wave;   // 0..15359
    int b = row / PP;
    int p = row - b * PP;
    int i = p / 15;
    int jj = p - i * 15;
    int j = jj + (jj >= i ? 1 : 0);
    const float* z1 = Z + ((size_t)(b * 16 + i)) * 1024;
    const float* z2 = Z + ((size_t)(b * 16 + j)) * 1024 + 512;
    float a0 = 0.f, a1 = 0.f, a2 = 0.f;
#pragma unroll
    for (int t = 0; t < 2; ++t) {
        int c = (lane + (t << 6)) << 2;      // 4-float chunk base
        float4 zv1 = *(const float4*)(z1 + c);
        float4 zv2 = *(const float4*)(z2 + c);
        float4 bv  = *(const float4*)(rb1 + c);
        float4 w0 = *(const float4*)(rw2 + c * 3);
        float4 w1 = *(const float4*)(rw2 + c * 3 + 4);
        float4 w2 = *(const float4*)(rw2 + c * 3 + 8);
        float fw[12] = {w0.x, w0.y, w0.z, w0.w, w1.x, w1.y, w1.z, w1.w, w2.x, w2.y, w2.z, w2.w};
        float h0 = ftanh(zv1.x + zv2.x + bv.x);
        float h1 = ftanh(zv1.y + zv2.y + bv.y);
        float h2 = ftanh(zv1.z + zv2.z + bv.z);
        float h3 = ftanh(zv1.w + zv2.w + bv.w);
        a0 += h0 * fw[0] + h1 * fw[3] + h2 * fw[6] + h3 * fw[9];
        a1 += h0 * fw[1] + h1 * fw[4] + h2 * fw[7] + h3 * fw[10];
        a2 += h0 * fw[2] + h1 * fw[5] + h2 * fw[8] + h3 * fw[11];
    }
#pragma unroll
    for (int off = 32; off >= 1; off >>= 1) {
        a0 += __shfl_down(a0, off);
        a1 += __shfl_down(a1, off);
        a2 += __shfl_down(a2, off);
    }
    if (lane == 0) {
        float l0 = a0 + rb2[0];
        float l1 = a1 + rb2[1];
        float l2 = a2 + rb2[2];
        float mxv = fmaxf(l0, fmaxf(l1, l2));
        float se = __expf(l0 - mxv) + __expf(l1 - mxv) + __expf(l2 - mxv);
        float lse = __logf(se) + mxv;
        int g = rels[row];
        float lg = (g == 0) ? l0 : ((g == 1) ? l1 : l2);
        red[wave] = lse - lg;
        float* o = out + 5120 + (size_t)row * 3;
        o[0] = l0; o[1] = l1; o[2] = l2;
    }
    __syncthreads();
    if (threadIdx.x == 0) {
        // tid0 wrote rel_p itself -> release on the RMW orders it; no threadfence needed
        rel_p[blockIdx.x] = red[0] + red[1] + red[2] + red[3];
        unsigned int old = __hip_atomic_fetch_add(cnt, 1u, __ATOMIC_ACQ_REL, __HIP_MEMORY_SCOPE_AGENT);
        isLast = (old == (unsigned int)(gridDim.x - 1));
    }
    __syncthreads();
    if (isLast) {
        __builtin_amdgcn_fence(__ATOMIC_ACQUIRE, "agent");  // once, in one block: cheap
        int tid = threadIdx.x;
        float sc = comp_p[tid] + comp_p[tid + 256] + comp_p[tid + 512] + comp_p[tid + 768];
        float sr = 0.f;
#pragma unroll
        for (int k = 0; k < 15; ++k) sr += rel_p[tid + k * 256];
#pragma unroll
        for (int off = 32; off >= 1; off >>= 1) {
            sc += __shfl_down(sc, off);
            sr += __shfl_down(sr, off);
        }
        if (lane == 0) { red[wave] = sc; red[4 + wave] = sr; }
        __syncthreads();
        if (tid == 0) {
            out[51200] = (red[0] + red[1] + red[2] + red[3]) * (1.0f / 1024.0f);
            out[51201] = (red[4] + red[5] + red[6] + red[7]) * (1.0f / 15360.0f);
        }
    }
}

extern "C" void kernel_launch(void* const* d_in, const int* in_sizes, int n_in,
                              void* d_out, int out_size, void* d_ws, size_t ws_size,
                              hipStream_t stream) {
    const float* lhs     = (const float*)d_in[0];
    const int* starts    = (const int*)d_in[1];
    const int* lens      = (const int*)d_in[2];
    const int* comps     = (const int*)d_in[3];
    const int* rels      = (const int*)d_in[4];
    const float* comp_w1 = (const float*)d_in[5];
    const float* comp_b1 = (const float*)d_in[6];
    const float* comp_w2 = (const float*)d_in[7];
    const float* comp_b2 = (const float*)d_in[8];
    const float* wq      = (const float*)d_in[9];
    const float* wk      = (const float*)d_in[10];
    const float* wv      = (const float*)d_in[11];
    const float* ln_g    = (const float*)d_in[12];
    const float* ln_b    = (const float*)d_in[13];
    const float* rel_w1  = (const float*)d_in[14];
    const float* rel_b1  = (const float*)d_in[15];
    const float* rel_w2  = (const float*)d_in[16];
    const float* rel_b2  = (const float*)d_in[17];
    float* out = (float*)d_out;
    float* ws = (float*)d_ws;

    float* pooled = ws;                       // 1024*768
    float* y2     = pooled + 786432;          // 1024*2816
    float* Z      = y2 + 2883584;             // 1024*1024
    float* comp_p = Z + 1048576;              // 1024
    float* rel_p  = comp_p + 1024;            // 3840
    u16* pooled_bf = (u16*)(rel_p + 3840);    // 786432 u16
    u16* x_bf      = pooled_bf + 786432;      // 786432
    u16* wcat_t    = x_bf + 786432;           // 2816*768
    u16* relw_t    = wcat_t + 2162688;        // 1024*768
    unsigned int* cnt = (unsigned int*)(ws + 8 * 1024 * 1024);  // +32MB, past all buffers

    (void)hipMemsetAsync(cnt, 0, 64, stream);
    prep_pool_kernel<<<3904, 256, 0, stream>>>(lhs, starts, lens, pooled, pooled_bf,
                                               comp_w1, wq, wk, wv, rel_w1, wcat_t, relw_t);
    gemm_pw_kernel<<<704, 256, 0, stream>>>(pooled_bf, wcat_t, comp_b1, y2);
    attn_ln_kernel<<<256, 256, 0, stream>>>(y2, pooled, ln_g, ln_b,
                                            comp_w2, comp_b2, comps, x_bf, out, comp_p);
    gemm_z_kernel<<<256, 256, 0, stream>>>(x_bf, relw_t, Z);
    heads_kernel<<<3840, 256, 0, stream>>>(Z, rel_b1, rel_w2, rel_b2, rels, comp_p,
                                           out, rel_p, cnt);
}

// Round 9
// 231.029 us; speedup vs baseline: 6.8515x; 1.4034x over previous
//
#include <hip/hip_runtime.h>

#define SS 512
#define HH 768
#define PP 240
#define CCOMP 5

typedef unsigned short u16;
typedef __attribute__((ext_vector_type(8))) short bf16x8;   // 8 bf16 in 4 VGPRs
typedef __attribute__((ext_vector_type(4))) float f32x4;

__device__ __forceinline__ u16 f2bf(float f) {
    union { float f; unsigned int i; } v; v.f = f;
    unsigned int x = v.i;
    unsigned int lsb = (x >> 16) & 1u;
    x += 0x7fffu + lsb;
    return (u16)(x >> 16);
}

__device__ __forceinline__ float ftanh(float x) {
    float xc = fminf(fmaxf(x, -15.f), 15.f);
    float e = __expf(2.f * xc);
    return (e - 1.f) / (e + 1.f);
}

// async global->LDS, 16B per lane; dest = wave-uniform base + lane*16
__device__ __forceinline__ void gl_lds16(const void* g, void* l) {
    __builtin_amdgcn_global_load_lds(
        (const __attribute__((address_space(1))) unsigned int*)g,
        (__attribute__((address_space(3))) unsigned int*)l, 16, 0, 0);
}

// ---------------- fused: span mean pooling (blocks 0..1023) + weight prep (1024..3903) ----------------
__global__ __launch_bounds__(256) void prep_pool_kernel(
    const float* __restrict__ lhs, const int* __restrict__ starts,
    const int* __restrict__ lens, float* __restrict__ pooled, u16* __restrict__ pooled_bf,
    const float* __restrict__ cw1, const float* __restrict__ wq,
    const float* __restrict__ wk, const float* __restrict__ wv,
    const float* __restrict__ rw1, u16* __restrict__ wcat_t, u16* __restrict__ relw_t) {
    int blk = blockIdx.x;
    int tid = threadIdx.x;
    if (blk < 1024) {
        if (tid >= 192) return;
        int st = starts[blk];
        int ln = lens[blk];
        int b = blk >> 4;
        const float4* base = (const float4*)(lhs + ((size_t)b * SS + st) * HH);
        float4 a = {0.f, 0.f, 0.f, 0.f};
        for (int s = 0; s <= ln; ++s) {
            float4 v = base[s * 192 + tid];
            a.x += v.x; a.y += v.y; a.z += v.z; a.w += v.w;
        }
        float inv = 1.0f / (float)(ln + 1);
        a.x *= inv; a.y *= inv; a.z *= inv; a.w *= inv;
        *(float4*)(pooled + (size_t)blk * HH + tid * 4) = a;
        ushort4 ub = { f2bf(a.x), f2bf(a.y), f2bf(a.z), f2bf(a.w) };
        *(ushort4*)(pooled_bf + (size_t)blk * HH + tid * 4) = ub;
        return;
    }
    blk -= 1024;
    const float* W; int ldw, nt; u16* outp;
    if (blk < 384)        {             W = cw1; ldw = 512; nt = 16; outp = wcat_t; }
    else if (blk < 960)   { blk -= 384; W = wq;  ldw = 768; nt = 24; outp = wcat_t + (size_t)512 * 768; }
    else if (blk < 1536)  { blk -= 960; W = wk;  ldw = 768; nt = 24; outp = wcat_t + (size_t)1280 * 768; }
    else if (blk < 2112)  { blk -= 1536; W = wv; ldw = 768; nt = 24; outp = wcat_t + (size_t)2048 * 768; }
    else if (blk < 2496)  { blk -= 2112; W = rw1; ldw = 512; nt = 16; outp = relw_t; }
    else                  { blk -= 2496; W = rw1 + (size_t)768 * 512; ldw = 512; nt = 16; outp = relw_t + (size_t)512 * 768; }
    int tk = blk / nt, tn = blk % nt;
    int k0 = tk * 32, n0 = tn * 32;
    __shared__ u16 Ls[32][36];
    int tx = tid & 31, ty = tid >> 5;
#pragma unroll
    for (int r = 0; r < 4; ++r) {
        int k = ty + r * 8;
        Ls[tx][k] = f2bf(W[(size_t)(k0 + k) * ldw + n0 + tx]);
    }
    __syncthreads();
#pragma unroll
    for (int r = 0; r < 4; ++r) {
        int n = ty + r * 8;
        outp[(size_t)(n0 + n) * 768 + k0 + tx] = Ls[n][tx];
    }
}

// 64x64-tile bf16 MFMA GEMM body: global_load_lds staging, XOR swizzle, 1-barrier dbuf.
// K = 768 fixed. Verified numerically in rounds 1/3/7/8.
__device__ __forceinline__ void gemm_tile(
    const u16* Abase, const u16* Bbase, u16* AsR, u16* BsR,
    int row0, int ccol0, int tid, f32x4 acc[2][2]) {
    int lane = tid & 63, w = tid >> 6;
    int q = lane >> 4, l15 = lane & 15;
    int wm = (w & 1) * 32, wn = (w >> 1) * 32;

    int srow = w * 8 + (lane >> 3);               // 0..31 (second issue adds +32)
    int sxs = ((lane & 7) * 16) ^ ((srow & 7) << 4);
    const char* gA0 = (const char*)(Abase + (size_t)(row0 + srow) * 768) + sxs;
    const char* gA1 = gA0 + (size_t)32 * 768 * 2;
    const char* gB0 = (const char*)(Bbase + (size_t)(ccol0 + srow) * 768) + sxs;
    const char* gB1 = gB0 + (size_t)32 * 768 * 2;
    char* lA = (char*)AsR + w * 1024;
    char* lB = (char*)BsR + w * 1024;

#pragma unroll
    for (int i = 0; i < 2; ++i)
#pragma unroll
        for (int j = 0; j < 2; ++j) acc[i][j] = (f32x4){0.f, 0.f, 0.f, 0.f};

#define STAGE_T(BUF, KB) do { \
        gl_lds16(gA0 + (KB), lA + (BUF) * 8192); \
        gl_lds16(gA1 + (KB), lA + (BUF) * 8192 + 4096); \
        gl_lds16(gB0 + (KB), lB + (BUF) * 8192); \
        gl_lds16(gB1 + (KB), lB + (BUF) * 8192 + 4096); \
    } while (0)

    STAGE_T(0, 0);
    asm volatile("s_waitcnt vmcnt(0)" ::: "memory");
    __syncthreads();
    int cur = 0;
    for (int t = 0; t < 12; ++t) {
        if (t < 11) STAGE_T(cur ^ 1, (t + 1) * 128);
        const char* Ab = (const char*)AsR + cur * 8192;
        const char* Bb = (const char*)BsR + cur * 8192;
#pragma unroll
        for (int ks = 0; ks < 2; ++ks) {
            int o = ks * 64 + q * 16;
            int Ra0 = wm + l15, Ra1 = wm + 16 + l15;
            int Rb0 = wn + l15, Rb1 = wn + 16 + l15;
            bf16x8 a0 = *(const bf16x8*)(Ab + Ra0 * 128 + (o ^ ((Ra0 & 7) << 4)));
            bf16x8 a1 = *(const bf16x8*)(Ab + Ra1 * 128 + (o ^ ((Ra1 & 7) << 4)));
            bf16x8 b0 = *(const bf16x8*)(Bb + Rb0 * 128 + (o ^ ((Rb0 & 7) << 4)));
            bf16x8 b1 = *(const bf16x8*)(Bb + Rb1 * 128 + (o ^ ((Rb1 & 7) << 4)));
            acc[0][0] = __builtin_amdgcn_mfma_f32_16x16x32_bf16(a0, b0, acc[0][0], 0, 0, 0);
            acc[0][1] = __builtin_amdgcn_mfma_f32_16x16x32_bf16(a0, b1, acc[0][1], 0, 0, 0);
            acc[1][0] = __builtin_amdgcn_mfma_f32_16x16x32_bf16(a1, b0, acc[1][0], 0, 0, 0);
            acc[1][1] = __builtin_amdgcn_mfma_f32_16x16x32_bf16(a1, b1, acc[1][1], 0, 0, 0);
        }
        asm volatile("s_waitcnt vmcnt(0)" ::: "memory");
        __syncthreads();
        cur ^= 1;
    }
#undef STAGE_T
}

// ---------------- y2[1024][2816] = [tanh(pooled@cw1+b1) | q | k | v] ----------------
__global__ __launch_bounds__(256) void gemm_pw_kernel(
    const u16* __restrict__ pooled_bf, const u16* __restrict__ wcat_t,
    const float* __restrict__ comp_b1, float* __restrict__ y2) {
    __shared__ u16 As[2][4096];
    __shared__ u16 Bs[2][4096];
    int bid = blockIdx.x;
    int sw = (bid & 7) * 88 + (bid >> 3);   // bijective XCD swizzle (704 = 8*88)
    int ct = sw >> 4, rt = sw & 15;
    int ccol0 = ct * 64, row0 = rt * 64;
    int act = (ccol0 < 512);
    int tid = threadIdx.x;
    int lane = tid & 63, w = tid >> 6;
    int q = lane >> 4, l15 = lane & 15;
    int wm = (w & 1) * 32, wn = (w >> 1) * 32;
    f32x4 acc[2][2];
    gemm_tile(pooled_bf, wcat_t, &As[0][0], &Bs[0][0], row0, ccol0, tid, acc);
    // C/D layout: col=lane&15, row=(lane>>4)*4+reg  [m89-verified]
#pragma unroll
    for (int tm = 0; tm < 2; ++tm)
#pragma unroll
        for (int tn = 0; tn < 2; ++tn)
#pragma unroll
            for (int reg = 0; reg < 4; ++reg) {
                int rr = row0 + wm + tm * 16 + q * 4 + reg;
                int cc = ccol0 + wn + tn * 16 + l15;
                float v = acc[tm][tn][reg];
                if (act) v = ftanh(v + comp_b1[cc]);
                y2[(size_t)rr * 2816 + cc] = v;
            }
}

// ---------------- attention + residual + LayerNorm + comp head (one wave per (b,n)) ----------------
__global__ __launch_bounds__(256) void attn_ln_kernel(
    const float* __restrict__ y2, const float* __restrict__ pooled,
    const float* __restrict__ ln_g, const float* __restrict__ ln_b,
    const float* __restrict__ cw2, const float* __restrict__ cb2,
    const int* __restrict__ comps,
    u16* __restrict__ x_bf, float* __restrict__ out, float* __restrict__ comp_p) {
    int w = threadIdx.x >> 6, l = threadIdx.x & 63;
    int gw = blockIdx.x * 4 + w;          // 0..1023
    int b = gw >> 4, n = gw & 15;
    const float* qrow = y2 + (size_t)(b * 16 + n) * 2816 + 512;
    float qv[12];
#pragma unroll
    for (int u = 0; u < 12; ++u) qv[u] = qrow[l + 64 * u];

    float s[16];
#pragma unroll
    for (int m = 0; m < 16; ++m) {
        const float* krow = y2 + (size_t)(b * 16 + m) * 2816 + 1280;
        float pv = 0.f;
#pragma unroll
        for (int u = 0; u < 12; ++u) pv += qv[u] * krow[l + 64 * u];
#pragma unroll
        for (int off = 32; off >= 1; off >>= 1) pv += __shfl_xor(pv, off);
        s[m] = pv * 0.03608439182435161f;   // 1/sqrt(768)
    }
    float mx = s[0];
#pragma unroll
    for (int m = 1; m < 16; ++m) mx = fmaxf(mx, s[m]);
    float den = 0.f;
#pragma unroll
    for (int m = 0; m < 16; ++m) { s[m] = __expf(s[m] - mx); den += s[m]; }
    float inv = 1.0f / den;

    float acc[12];
#pragma unroll
    for (int u = 0; u < 12; ++u) acc[u] = 0.f;
#pragma unroll
    for (int m = 0; m < 16; ++m) {
        const float* vrow = y2 + (size_t)(b * 16 + m) * 2816 + 2048;
        float pm = s[m] * inv;
#pragma unroll
        for (int u = 0; u < 12; ++u) acc[u] += pm * vrow[l + 64 * u];
    }

    int row = b * 16 + n;
    const float* prow = pooled + (size_t)row * HH;
    float xv[12];
    float ssum = 0.f, ssq = 0.f;
#pragma unroll
    for (int u = 0; u < 12; ++u) {
        float v = prow[l + 64 * u] + acc[u];
        xv[u] = v;
        ssum += v;
        ssq += v * v;
    }
#pragma unroll
    for (int off = 32; off >= 1; off >>= 1) {
        ssum += __shfl_xor(ssum, off);
        ssq += __shfl_xor(ssq, off);
    }
    float mu = ssum * (1.0f / 768.0f);
    float var = ssq * (1.0f / 768.0f) - mu * mu;
    float rs = rsqrtf(var + 1e-5f);
    u16* xrow_bf = x_bf + (size_t)row * HH;
#pragma unroll
    for (int u = 0; u < 12; ++u) {
        int h = l + 64 * u;
        xrow_bf[h] = f2bf((xv[u] - mu) * rs * ln_g[h] + ln_b[h]);
    }

    // ---- comp head for this row (y2[row][0..512] ready since gemm_pw) ----
    const float* hrow = y2 + (size_t)row * 2816;
    float ac[CCOMP] = {0.f, 0.f, 0.f, 0.f, 0.f};
#pragma unroll
    for (int t = 0; t < 2; ++t) {
        int c = (l + (t << 6)) << 2;
        float4 hv = *(const float4*)(hrow + c);
        float4 g0 = *(const float4*)(cw2 + c * 5);
        float4 g1 = *(const float4*)(cw2 + c * 5 + 4);
        float4 g2 = *(const float4*)(cw2 + c * 5 + 8);
        float4 g3 = *(const float4*)(cw2 + c * 5 + 12);
        float4 g4 = *(const float4*)(cw2 + c * 5 + 16);
        float fw[20] = {g0.x, g0.y, g0.z, g0.w, g1.x, g1.y, g1.z, g1.w,
                        g2.x, g2.y, g2.z, g2.w, g3.x, g3.y, g3.z, g3.w,
                        g4.x, g4.y, g4.z, g4.w};
        float hh[4] = {hv.x, hv.y, hv.z, hv.w};
#pragma unroll
        for (int jj = 0; jj < 4; ++jj)
#pragma unroll
            for (int cc = 0; cc < CCOMP; ++cc) ac[cc] += hh[jj] * fw[5 * jj + cc];
    }
#pragma unroll
    for (int cc = 0; cc < CCOMP; ++cc)
#pragma unroll
        for (int off = 32; off >= 1; off >>= 1) ac[cc] += __shfl_down(ac[cc], off);
    if (l == 0) {
        float lg[CCOMP];
        float mxv = -1e30f;
#pragma unroll
        for (int cc = 0; cc < CCOMP; ++cc) { lg[cc] = ac[cc] + cb2[cc]; mxv = fmaxf(mxv, lg[cc]); }
        float se = 0.f;
#pragma unroll
        for (int cc = 0; cc < CCOMP; ++cc) se += __expf(lg[cc] - mxv);
        float lse = __logf(se) + mxv;
        comp_p[row] = lse - lg[comps[row]];
#pragma unroll
        for (int cc = 0; cc < CCOMP; ++cc) out[row * CCOMP + cc] = lg[cc];
    }
}

// ---------------- Z[1024][1024] = x @ [W_top | W_bot] ----------------
__global__ __launch_bounds__(256) void gemm_z_kernel(
    const u16* __restrict__ x_bf, const u16* __restrict__ relw_t, float* __restrict__ Z) {
    __shared__ u16 As[2][4096];
    __shared__ u16 Bs[2][4096];
    int bid = blockIdx.x;
    int sw = (bid & 7) * 32 + (bid >> 3);   // bijective (256 = 8*32)
    int ct = sw >> 4, rt = sw & 15;
    int ccol0 = ct * 64, row0 = rt * 64;
    int tid = threadIdx.x;
    int lane = tid & 63, w = tid >> 6;
    int q = lane >> 4, l15 = lane & 15;
    int wm = (w & 1) * 32, wn = (w >> 1) * 32;
    f32x4 acc[2][2];
    gemm_tile(x_bf, relw_t, &As[0][0], &Bs[0][0], row0, ccol0, tid, acc);
#pragma unroll
    for (int tm = 0; tm < 2; ++tm)
#pragma unroll
        for (int tn = 0; tn < 2; ++tn)
#pragma unroll
            for (int reg = 0; reg < 4; ++reg) {
                int rr = row0 + wm + tm * 16 + q * 4 + reg;
                int cc = ccol0 + wn + tn * 16 + l15;
                Z[(size_t)rr * 1024 + cc] = acc[tm][tn][reg];
            }
}

// ---------------- rel head (3840 blocks), NO atomics (L2-invalidate law: acquire ops O(1)/kernel) ----------------
__global__ __launch_bounds__(256) void heads_kernel(
    const float* __restrict__ Z, const float* __restrict__ rb1,
    const float* __restrict__ rw2, const float* __restrict__ rb2,
    const int* __restrict__ rels,
    float* __restrict__ out, float* __restrict__ rel_p) {
    __shared__ float red[4];
    int wave = threadIdx.x >> 6, lane = threadIdx.x & 63;
    int row = blockIdx.x * 4 + wave;   // 0..15359
    int b = row / PP;
    int p = row - b * PP;
    int i = p / 15;
    int jj = p - i * 15;
    int j = jj + (jj >= i ? 1 : 0);
    const float* z1 = Z + ((size_t)(b * 16 + i)) * 1024;
    const float* z2 = Z + ((size_t)(b * 16 + j)) * 1024 + 512;
    float a0 = 0.f, a1 = 0.f, a2 = 0.f;
#pragma unroll
    for (int t = 0; t < 2; ++t) {
        int c = (lane + (t << 6)) << 2;      // 4-float chunk base
        float4 zv1 = *(const float4*)(z1 + c);
        float4 zv2 = *(const float4*)(z2 + c);
        float4 bv  = *(const float4*)(rb1 + c);
        float4 w0 = *(const float4*)(rw2 + c * 3);
        float4 w1 = *(const float4*)(rw2 + c * 3 + 4);
        float4 w2 = *(const float4*)(rw2 + c * 3 + 8);
        float fw[12] = {w0.x, w0.y, w0.z, w0.w, w1.x, w1.y, w1.z, w1.w, w2.x, w2.y, w2.z, w2.w};
        float h0 = ftanh(zv1.x + zv2.x + bv.x);
        float h1 = ftanh(zv1.y + zv2.y + bv.y);
        float h2 = ftanh(zv1.z + zv2.z + bv.z);
        float h3 = ftanh(zv1.w + zv2.w + bv.w);
        a0 += h0 * fw[0] + h1 * fw[3] + h2 * fw[6] + h3 * fw[9];
        a1 += h0 * fw[1] + h1 * fw[4] + h2 * fw[7] + h3 * fw[10];
        a2 += h0 * fw[2] + h1 * fw[5] + h2 * fw[8] + h3 * fw[11];
    }
#pragma unroll
    for (int off = 32; off >= 1; off >>= 1) {
        a0 += __shfl_down(a0, off);
        a1 += __shfl_down(a1, off);
        a2 += __shfl_down(a2, off);
    }
    if (lane == 0) {
        float l0 = a0 + rb2[0];
        float l1 = a1 + rb2[1];
        float l2 = a2 + rb2[2];
        float mxv = fmaxf(l0, fmaxf(l1, l2));
        float se = __expf(l0 - mxv) + __expf(l1 - mxv) + __expf(l2 - mxv);
        float lse = __logf(se) + mxv;
        int g = rels[row];
        float lg = (g == 0) ? l0 : ((g == 1) ? l1 : l2);
        red[wave] = lse - lg;
        float* o = out + 5120 + (size_t)row * 3;
        o[0] = l0; o[1] = l1; o[2] = l2;
    }
    __syncthreads();
    if (threadIdx.x == 0) rel_p[blockIdx.x] = red[0] + red[1] + red[2] + red[3];
}

// ---------------- final loss reduction ----------------
__global__ __launch_bounds__(256) void finalize_kernel(
    const float* __restrict__ comp_p, const float* __restrict__ rel_p,
    float* __restrict__ out) {
    __shared__ float rc[4], rr[4];
    int tid = threadIdx.x;
    int wave = tid >> 6, lane = tid & 63;
    float sc = comp_p[tid] + comp_p[tid + 256] + comp_p[tid + 512] + comp_p[tid + 768];
    float sr = 0.f;
#pragma unroll
    for (int k = 0; k < 15; ++k) sr += rel_p[tid + k * 256];
#pragma unroll
    for (int off = 32; off >= 1; off >>= 1) {
        sc += __shfl_down(sc, off);
        sr += __shfl_down(sr, off);
    }
    if (lane == 0) { rc[wave] = sc; rr[wave] = sr; }
    __syncthreads();
    if (tid == 0) {
        out[51200] = (rc[0] + rc[1] + rc[2] + rc[3]) * (1.0f / 1024.0f);
        out[51201] = (rr[0] + rr[1] + rr[2] + rr[3]) * (1.0f / 15360.0f);
    }
}

extern "C" void kernel_launch(void* const* d_in, const int* in_sizes, int n_in,
                              void* d_out, int out_size, void* d_ws, size_t ws_size,
                              hipStream_t stream) {
    const float* lhs     = (const float*)d_in[0];
    const int* starts    = (const int*)d_in[1];
    const int* lens      = (const int*)d_in[2];
    const int* comps     = (const int*)d_in[3];
    const int* rels      = (const int*)d_in[4];
    const float* comp_w1 = (const float*)d_in[5];
    const float* comp_b1 = (const float*)d_in[6];
    const float* comp_w2 = (const float*)d_in[7];
    const float* comp_b2 = (const float*)d_in[8];
    const float* wq      = (const float*)d_in[9];
    const float* wk      = (const float*)d_in[10];
    const float* wv      = (const float*)d_in[11];
    const float* ln_g    = (const float*)d_in[12];
    const float* ln_b    = (const float*)d_in[13];
    const float* rel_w1  = (const float*)d_in[14];
    const float* rel_b1  = (const float*)d_in[15];
    const float* rel_w2  = (const float*)d_in[16];
    const float* rel_b2  = (const float*)d_in[17];
    float* out = (float*)d_out;
    float* ws = (float*)d_ws;

    float* pooled = ws;                       // 1024*768
    float* y2     = pooled + 786432;          // 1024*2816
    float* Z      = y2 + 2883584;             // 1024*1024
    float* comp_p = Z + 1048576;              // 1024
    float* rel_p  = comp_p + 1024;            // 3840
    u16* pooled_bf = (u16*)(rel_p + 3840);    // 786432 u16
    u16* x_bf      = pooled_bf + 786432;      // 786432
    u16* wcat_t    = x_bf + 786432;           // 2816*768
    u16* relw_t    = wcat_t + 2162688;        // 1024*768

    prep_pool_kernel<<<3904, 256, 0, stream>>>(lhs, starts, lens, pooled, pooled_bf,
                                               comp_w1, wq, wk, wv, rel_w1, wcat_t, relw_t);
    gemm_pw_kernel<<<704, 256, 0, stream>>>(pooled_bf, wcat_t, comp_b1, y2);
    attn_ln_kernel<<<256, 256, 0, stream>>>(y2, pooled, ln_g, ln_b,
                                            comp_w2, comp_b2, comps, x_bf, out, comp_p);
    gemm_z_kernel<<<256, 256, 0, stream>>>(x_bf, relw_t, Z);
    heads_kernel<<<3840, 256, 0, stream>>>(Z, rel_b1, rel_w2, rel_b2, rels, out, rel_p);
    finalize_kernel<<<1, 256, 0, stream>>>(comp_p, rel_p, out);
}